// Round 1
// baseline (19203.407 us; speedup 1.0000x reference)
//
#include <hip/hip_runtime.h>

// ---------------------------------------------------------------------------
// MTSLTM (time-aware LSTM), B=64 T=512 D=256 H=512.
// Persistent-kernel design: 256 blocks x 512 threads, all co-resident
// (1 block/CU). Grid split: 8 batch-groups (8 batches each) x 32 col-slices
// (16 h-cols each). Per time step, blocks of a group exchange h (through
// d_out's hidden_seq rows) and c (double-buffered in d_ws), synchronizing
// via a per-group monotonic atomic counter with release/acquire semantics
// (agent scope -> correct across XCD L2s).
// ---------------------------------------------------------------------------

constexpr int kB = 64, kT = 512, kD = 256, kH = 512, kG = 2048;
constexpr int NBLK = 256, NTHR = 512;
constexpr int BPG = 8;     // batches per group
constexpr int CPS = 16;    // h-cols per slice
constexpr int GRP = 32;    // blocks per group (= #slices)
constexpr int HP  = kH + 4; // padded LDS row (breaks batch-row bank aliasing)
constexpr int DP  = kD + 4;

__device__ __forceinline__ float fsig(float x)  { return 1.0f / (1.0f + __expf(-x)); }
__device__ __forceinline__ float ftanh(float x) { return 2.0f / (1.0f + __expf(-2.0f * x)) - 1.0f; }

__global__ __launch_bounds__(NTHR, 1) void mtsltm_kernel(
    const float* __restrict__ inp, const float* __restrict__ tdel,
    const float* __restrict__ Wd,  const float* __restrict__ W,
    const float* __restrict__ U,   const float* __restrict__ bias,
    float* __restrict__ out, float* cbuf, unsigned* cnt)
{
  __shared__ float h_lds[BPG][HP];
  __shared__ float c_lds[BPG][HP];
  __shared__ float x_lds[BPG][DP];
  __shared__ float g_lds[BPG][64];   // gate pre-activations for this slice
  __shared__ float s_lds[BPG][CPS];  // tanh(c @ W_d) for this slice

  const int tid = threadIdx.x;
  const int cs  = blockIdx.x & 31;   // col slice (bid%8 == cs%8 -> same-slice blocks share an XCD under round-robin)
  const int bg  = blockIdx.x >> 5;   // batch group

  // ---- phase A roles: wave wv covers gate cols [wv*8, wv*8+8) of the slice,
  //      lanes = 4 col-pairs x 8 batches x 2 k-halves ----
  const int wv   = tid >> 6;
  const int ln   = tid & 63;
  const int a_cp = ln & 3;
  const int a_b  = (ln >> 2) & 7;
  const int a_kh = ln >> 5;
  const int a_gc = wv * 8 + a_cp * 2;                    // [0,64), even
  const int a_Gc = (a_gc >> 4) * kH + cs * CPS + (a_gc & 15); // global gate col

  // ---- phase B roles: (batch=wave) x 16 cols x 4 k-quarters (k interleaved) ----
  const int b_kq = tid & 3;
  const int b_j  = (tid >> 2) & 15;
  const int b_b  = tid >> 6;

  unsigned* myc = cnt + bg * 32;     // 128B-spaced counters per group
  const size_t HID = (size_t)kB * kT * kH;

  for (int t = 0; t < kT; ++t) {
    // ------------------- stage h, c, x into LDS -------------------
    if (t == 0) {
      for (int i4 = tid; i4 < BPG * (kH / 4); i4 += NTHR) {
        int bb = i4 >> 7, c4 = (i4 & 127) * 4;
        float4 z = make_float4(0.f, 0.f, 0.f, 0.f);
        *(float4*)&h_lds[bb][c4] = z;
        *(float4*)&c_lds[bb][c4] = z;
      }
    } else {
      for (int i4 = tid; i4 < BPG * (kH / 4); i4 += NTHR) {
        int bb = i4 >> 7, c4 = (i4 & 127) * 4;
        int bbg = bg * BPG + bb;
        *(float4*)&h_lds[bb][c4] =
            *(const float4*)&out[((size_t)bbg * kT + (t - 1)) * kH + c4];
        *(float4*)&c_lds[bb][c4] =
            *(const float4*)&cbuf[(size_t)((t - 1) & 1) * kB * kH + (size_t)bbg * kH + c4];
      }
    }
    {
      int bb = tid >> 6, d4 = (tid & 63) * 4;   // 512 chunks exactly
      *(float4*)&x_lds[bb][d4] =
          *(const float4*)&inp[((size_t)(bg * BPG + bb) * kT + t) * kD + d4];
    }
    __syncthreads();

    // ------------------- phase A: gates = x@W + h@U (+bias) -------------------
    {
      float ax = 0.f, ay = 0.f;
      const float* hp = h_lds[a_b];
      const float* up = U + a_Gc;
      const int k0 = a_kh * 256;
      #pragma unroll 4
      for (int k = k0; k < k0 + 256; k += 4) {
        float4 hv = *(const float4*)&hp[k];
        float2 u0 = *(const float2*)&up[(size_t)(k + 0) * kG];
        float2 u1 = *(const float2*)&up[(size_t)(k + 1) * kG];
        float2 u2 = *(const float2*)&up[(size_t)(k + 2) * kG];
        float2 u3 = *(const float2*)&up[(size_t)(k + 3) * kG];
        ax = fmaf(hv.x, u0.x, ax); ay = fmaf(hv.x, u0.y, ay);
        ax = fmaf(hv.y, u1.x, ax); ay = fmaf(hv.y, u1.y, ay);
        ax = fmaf(hv.z, u2.x, ax); ay = fmaf(hv.z, u2.y, ay);
        ax = fmaf(hv.w, u3.x, ax); ay = fmaf(hv.w, u3.y, ay);
      }
      const float* xp = x_lds[a_b];
      const float* wp = W + a_Gc;
      const int k1 = a_kh * 128;
      #pragma unroll 4
      for (int k = k1; k < k1 + 128; k += 4) {
        float4 xv = *(const float4*)&xp[k];
        float2 w0 = *(const float2*)&wp[(size_t)(k + 0) * kG];
        float2 w1 = *(const float2*)&wp[(size_t)(k + 1) * kG];
        float2 w2 = *(const float2*)&wp[(size_t)(k + 2) * kG];
        float2 w3 = *(const float2*)&wp[(size_t)(k + 3) * kG];
        ax = fmaf(xv.x, w0.x, ax); ay = fmaf(xv.x, w0.y, ay);
        ax = fmaf(xv.y, w1.x, ax); ay = fmaf(xv.y, w1.y, ay);
        ax = fmaf(xv.z, w2.x, ax); ay = fmaf(xv.z, w2.y, ay);
        ax = fmaf(xv.w, w3.x, ax); ay = fmaf(xv.w, w3.y, ay);
      }
      ax += __shfl_xor(ax, 32);
      ay += __shfl_xor(ay, 32);
      if (a_kh == 0) {
        g_lds[a_b][a_gc]     = ax + bias[a_Gc];
        g_lds[a_b][a_gc + 1] = ay + bias[a_Gc + 1];
      }
    }

    // ------------------- phase B: c_s = tanh(c @ W_d) -------------------
    {
      const float* cp  = c_lds[b_b];
      const float* wdp = Wd + cs * CPS + b_j;
      float p = 0.f;
      #pragma unroll 8
      for (int kk = 0; kk < 128; ++kk) {
        int k = kk * 4 + b_kq;           // interleaved k: adjacent lanes -> adjacent k
        p = fmaf(cp[k], wdp[(size_t)k * kH], p);
      }
      p += __shfl_xor(p, 1);
      p += __shfl_xor(p, 2);
      if (b_kq == 0) s_lds[b_b][b_j] = ftanh(p);
    }
    __syncthreads();

    // ------------------- pointwise cell update -------------------
    if (tid < BPG * CPS) {
      int pb = tid >> 4, pj = tid & 15;
      int jg  = cs * CPS + pj;
      int pbg = bg * BPG + pb;
      float cprev = c_lds[pb][jg];
      float csv   = s_lds[pb][pj];
      float td    = tdel[(size_t)pbg * kT + t];
      float cadj  = (cprev - csv) + csv / __logf(2.71828182845904523536f + td);
      float gi = fsig (g_lds[pb][pj]);
      float gf = fsig (g_lds[pb][CPS + pj]);
      float gg = ftanh(g_lds[pb][2 * CPS + pj]);
      float go = fsig (g_lds[pb][3 * CPS + pj]);
      float cnew = fmaf(gf, cadj, gi * gg);
      float hout = ftanh(go * ftanh(cnew));
      float cout = ftanh(cnew);
      out[((size_t)pbg * kT + t) * kH + jg] = hout;
      cbuf[(size_t)(t & 1) * kB * kH + (size_t)pbg * kH + jg] = cout;
      if (t == kT - 1) {
        out[HID + (size_t)pbg * kH + jg] = hout;                       // h_t
        out[HID + (size_t)kB * kH + (size_t)pbg * kH + jg] = cout;     // c_t
      }
    }

    // ------------------- group barrier (release/acquire, agent scope) -------------------
    __syncthreads();   // drains this block's stores (vmcnt) before release
    if (tid == 0) {
      __hip_atomic_fetch_add(myc, 1u, __ATOMIC_RELEASE, __HIP_MEMORY_SCOPE_AGENT);
      const unsigned tgt = (unsigned)(GRP * (t + 1));
      int spins = 0;
      while (__hip_atomic_load(myc, __ATOMIC_RELAXED, __HIP_MEMORY_SCOPE_AGENT) < tgt) {
        if (++spins > (1 << 20)) break;   // safety valve: never hard-hang
      }
      __builtin_amdgcn_fence(__ATOMIC_ACQUIRE, "agent");  // invalidate stale L2/L1 lines
    }
    __syncthreads();
  }
}

extern "C" void kernel_launch(void* const* d_in, const int* in_sizes, int n_in,
                              void* d_out, int out_size, void* d_ws, size_t ws_size,
                              hipStream_t stream)
{
  const float* inp  = (const float*)d_in[0];
  const float* td   = (const float*)d_in[1];
  const float* Wd   = (const float*)d_in[2];
  const float* W    = (const float*)d_in[3];
  const float* U    = (const float*)d_in[4];
  const float* bias = (const float*)d_in[5];
  float* out = (float*)d_out;

  // ws layout: [0, 256KB) c double-buffer, then per-group sync counters.
  float*    cbuf = (float*)d_ws;
  unsigned* cnt  = (unsigned*)((char*)d_ws + (size_t)2 * kB * kH * sizeof(float));

  hipMemsetAsync(cnt, 0, (kB / BPG) * 32 * sizeof(unsigned), stream);
  mtsltm_kernel<<<dim3(NBLK), dim3(NTHR), 0, stream>>>(inp, td, Wd, W, U, bias,
                                                       out, cbuf, cnt);
}

// Round 2
// 6535.664 us; speedup vs baseline: 2.9382x; 2.9382x over previous
//
#include <hip/hip_runtime.h>

// ---------------------------------------------------------------------------
// MTSLTM (time-aware LSTM), B=64 T=512 D=256 H=512.
// Persistent kernel: 256 blocks x 512 threads, 1 block/CU, co-resident.
// Split: 32 col-slices (16 h-cols each) x 8 batch-groups (8 batches each),
// bg = bid&7 so each sync group maps to one XCD under round-robin dispatch.
//
// Key change vs r1: ALL weights live in VGPRs (loaded once at t=0):
//   phase A: lane = gate-col (64 cols), wave = k-chunk (64 h-k + 32 x-k),
//            per-thread wA[96]; h/x broadcast from LDS (uniform ds_read_b128).
//   phase B: lane = (q,j), per-thread wB[16] of W_d.
// Per-step global traffic = h/c/x restage (~40 KB/block) + flag barrier.
// ---------------------------------------------------------------------------

constexpr int kB = 64, kT = 512, kD = 256, kH = 512, kG = 2048;
constexpr int NBLK = 256, NTHR = 512;
constexpr int BPG  = 8;    // batches per group
constexpr int GRP  = 32;   // blocks per sync group (= #slices)

__device__ __forceinline__ float fsig(float x)  { return 1.0f / (1.0f + __expf(-x)); }
__device__ __forceinline__ float ftanh(float x) { return 2.0f / (1.0f + __expf(-2.0f * x)) - 1.0f; }

__global__ __launch_bounds__(NTHR, 2) void mtsltm_kernel(
    const float* __restrict__ inp, const float* __restrict__ tdel,
    const float* __restrict__ Wd,  const float* __restrict__ W,
    const float* __restrict__ U,   const float* __restrict__ bias,
    float* __restrict__ out, float* __restrict__ cbuf, unsigned* __restrict__ flags)
{
  __shared__ float h_lds[BPG][kH];     // 16 KB  (prev h, this group's batches)
  __shared__ float c_lds[BPG][kH];     // 16 KB  (prev c)
  __shared__ float x_lds[BPG][kD];     // 8 KB   (x_t)
  __shared__ float g_part[8][BPG][64]; // 16 KB  (per-wave gate partials)
  __shared__ float s_part[8][BPG][16]; // 4 KB   (per-wave Wd partials)
  __shared__ float s_td[BPG];

  const int tid = threadIdx.x;
  const int bid = blockIdx.x;
  const int bg  = bid & 7;    // batch group -> same XCD under round-robin
  const int cs  = bid >> 3;   // col slice [0,32)
  const int wv  = tid >> 6;   // wave [0,8)
  const int ln  = tid & 63;

  // ---- phase A identity: lane = gate col of slice ----
  const int aj   = ln & 15;              // h-col within slice
  const int agt  = ln >> 4;              // gate 0..3 (i,f,g,o)
  const int gcol = agt * kH + cs * 16 + aj;

  // ---- phase B identity: lane = (q, j) ----
  const int bq = ln >> 4;                // k-subchunk 0..3
  const int bj = ln & 15;                // Wd col within slice
  const int wdcol = cs * 16 + bj;

  // ================= one-time: weights -> VGPRs =================
  float wA[96];
  {
    const float* up = U + gcol;
    #pragma unroll
    for (int kk = 0; kk < 64; ++kk)
      wA[kk] = up[(size_t)(wv * 64 + kk) * kG];
    const float* wp = W + gcol;
    #pragma unroll
    for (int kk = 0; kk < 32; ++kk)
      wA[64 + kk] = wp[(size_t)(wv * 32 + kk) * kG];
  }
  float wB[16];
  {
    #pragma unroll
    for (int m = 0; m < 4; ++m)
      #pragma unroll
      for (int u = 0; u < 4; ++u)
        wB[m * 4 + u] = Wd[(size_t)(wv * 64 + bq * 4 + m * 16 + u) * kH + wdcol];
  }
  float bias_r[4] = {0.f, 0.f, 0.f, 0.f};
  if (tid < BPG * 16) {
    int jj = tid & 15;
    #pragma unroll
    for (int g = 0; g < 4; ++g) bias_r[g] = bias[g * kH + cs * 16 + jj];
  }

  const size_t HID = (size_t)kB * kT * kH;

  for (int t = 0; t < kT; ++t) {
    // ================= stage h, c, x, td into LDS =================
    if (t == 0) {
      for (int i = tid; i < BPG * (kH / 4); i += NTHR) {
        int bb = i >> 7, c4 = (i & 127) * 4;
        float4 z = make_float4(0.f, 0.f, 0.f, 0.f);
        *(float4*)&h_lds[bb][c4] = z;
        *(float4*)&c_lds[bb][c4] = z;
      }
    } else {
      for (int i = tid; i < BPG * (kH / 4); i += NTHR) {
        int bb = i >> 7, c4 = (i & 127) * 4;
        int bgl = bg * BPG + bb;
        *(float4*)&h_lds[bb][c4] =
            *(const float4*)&out[((size_t)bgl * kT + (t - 1)) * kH + c4];
        *(float4*)&c_lds[bb][c4] =
            *(const float4*)&cbuf[(size_t)((t - 1) & 1) * kB * kH + (size_t)bgl * kH + c4];
      }
    }
    {
      int bb = tid >> 6, d4 = (tid & 63) * 4;   // exactly 512 float4 chunks
      *(float4*)&x_lds[bb][d4] =
          *(const float4*)&inp[((size_t)(bg * BPG + bb) * kT + t) * kD + d4];
    }
    if (tid < BPG) s_td[tid] = tdel[(size_t)(bg * BPG + tid) * kT + t];
    __syncthreads();

    // ================= phase A: gates partials (VGPR weights) =================
    {
      float acc[8] = {0.f, 0.f, 0.f, 0.f, 0.f, 0.f, 0.f, 0.f};
      // h part: k in [wv*64, wv*64+64)
      #pragma unroll
      for (int m = 0; m < 16; ++m) {
        float4 hv[8];
        #pragma unroll
        for (int b = 0; b < 8; ++b) hv[b] = *(const float4*)&h_lds[b][wv * 64 + m * 4];
        #pragma unroll
        for (int b = 0; b < 8; ++b) {
          acc[b] = fmaf(wA[m * 4 + 0], hv[b].x, acc[b]);
          acc[b] = fmaf(wA[m * 4 + 1], hv[b].y, acc[b]);
          acc[b] = fmaf(wA[m * 4 + 2], hv[b].z, acc[b]);
          acc[b] = fmaf(wA[m * 4 + 3], hv[b].w, acc[b]);
        }
      }
      // x part: k in [wv*32, wv*32+32)
      #pragma unroll
      for (int m = 0; m < 8; ++m) {
        float4 xv[8];
        #pragma unroll
        for (int b = 0; b < 8; ++b) xv[b] = *(const float4*)&x_lds[b][wv * 32 + m * 4];
        #pragma unroll
        for (int b = 0; b < 8; ++b) {
          acc[b] = fmaf(wA[64 + m * 4 + 0], xv[b].x, acc[b]);
          acc[b] = fmaf(wA[64 + m * 4 + 1], xv[b].y, acc[b]);
          acc[b] = fmaf(wA[64 + m * 4 + 2], xv[b].z, acc[b]);
          acc[b] = fmaf(wA[64 + m * 4 + 3], xv[b].w, acc[b]);
        }
      }
      #pragma unroll
      for (int b = 0; b < 8; ++b) g_part[wv][b][ln] = acc[b];
    }

    // ================= phase B: Wd partials =================
    {
      float accw[8] = {0.f, 0.f, 0.f, 0.f, 0.f, 0.f, 0.f, 0.f};
      #pragma unroll
      for (int m = 0; m < 4; ++m) {
        float4 cv[8];
        #pragma unroll
        for (int b = 0; b < 8; ++b)
          cv[b] = *(const float4*)&c_lds[b][wv * 64 + bq * 4 + m * 16];
        #pragma unroll
        for (int b = 0; b < 8; ++b) {
          accw[b] = fmaf(wB[m * 4 + 0], cv[b].x, accw[b]);
          accw[b] = fmaf(wB[m * 4 + 1], cv[b].y, accw[b]);
          accw[b] = fmaf(wB[m * 4 + 2], cv[b].z, accw[b]);
          accw[b] = fmaf(wB[m * 4 + 3], cv[b].w, accw[b]);
        }
      }
      #pragma unroll
      for (int b = 0; b < 8; ++b) {
        accw[b] += __shfl_xor(accw[b], 16);
        accw[b] += __shfl_xor(accw[b], 32);
      }
      if (bq == 0) {
        #pragma unroll
        for (int b = 0; b < 8; ++b) s_part[wv][b][bj] = accw[b];
      }
    }
    __syncthreads();

    // ================= pointwise cell update =================
    if (tid < BPG * 16) {
      int b = tid >> 4, jj = tid & 15;
      float s0 = 0.f, s1 = 0.f, s2 = 0.f, s3 = 0.f, sw = 0.f;
      #pragma unroll
      for (int w = 0; w < 8; ++w) {
        s0 += g_part[w][b][jj];
        s1 += g_part[w][b][16 + jj];
        s2 += g_part[w][b][32 + jj];
        s3 += g_part[w][b][48 + jj];
        sw += s_part[w][b][jj];
      }
      int col = cs * 16 + jj;
      int bgl = bg * BPG + b;
      float csv   = ftanh(sw);
      float cprev = c_lds[b][col];
      float td    = s_td[b];
      float cadj  = (cprev - csv) + csv / __logf(2.71828182845904523536f + td);
      float gi = fsig (s0 + bias_r[0]);
      float gf = fsig (s1 + bias_r[1]);
      float gg = ftanh(s2 + bias_r[2]);
      float go = fsig (s3 + bias_r[3]);
      float cnew = fmaf(gf, cadj, gi * gg);
      float hout = ftanh(go * ftanh(cnew));
      float cout = ftanh(cnew);
      out[((size_t)bgl * kT + t) * kH + col] = hout;
      cbuf[(size_t)(t & 1) * kB * kH + (size_t)bgl * kH + col] = cout;
      if (t == kT - 1) {
        out[HID + (size_t)bgl * kH + col] = hout;
        out[HID + (size_t)kB * kH + (size_t)bgl * kH + col] = cout;
      }
    }

    // ================= flag barrier (release store + lane-parallel poll) ======
    __syncthreads();   // all waves' stores drained (vmcnt) before release
    if (tid == 0)
      __hip_atomic_store(&flags[bid * 32], (unsigned)(t + 1),
                         __ATOMIC_RELEASE, __HIP_MEMORY_SCOPE_AGENT);
    if (wv == 0) {
      const int member = ((ln & 31) * 8 + bg) * 32;   // 32 group members, 128B apart
      int spins = 0;
      for (;;) {
        unsigned v = __hip_atomic_load(&flags[member], __ATOMIC_RELAXED,
                                       __HIP_MEMORY_SCOPE_AGENT);
        if (__all(v > (unsigned)t)) break;
        if (++spins > (1 << 20)) break;   // safety valve: never hard-hang
      }
      __builtin_amdgcn_fence(__ATOMIC_ACQUIRE, "agent");
    }
    __syncthreads();
  }
}

extern "C" void kernel_launch(void* const* d_in, const int* in_sizes, int n_in,
                              void* d_out, int out_size, void* d_ws, size_t ws_size,
                              hipStream_t stream)
{
  const float* inp  = (const float*)d_in[0];
  const float* td   = (const float*)d_in[1];
  const float* Wd   = (const float*)d_in[2];
  const float* W    = (const float*)d_in[3];
  const float* U    = (const float*)d_in[4];
  const float* bias = (const float*)d_in[5];
  float* out = (float*)d_out;

  // ws layout: [0, 256KB) c double-buffer; then 256 flags, 128 B apart.
  float*    cbuf  = (float*)d_ws;
  unsigned* flags = (unsigned*)((char*)d_ws + (size_t)2 * kB * kH * sizeof(float));

  hipMemsetAsync(flags, 0, NBLK * 32 * sizeof(unsigned), stream);
  mtsltm_kernel<<<dim3(NBLK), dim3(NTHR), 0, stream>>>(inp, td, Wd, W, U, bias,
                                                       out, cbuf, flags);
}

// Round 3
// 4991.164 us; speedup vs baseline: 3.8475x; 1.3094x over previous
//
#include <hip/hip_runtime.h>

// ---------------------------------------------------------------------------
// MTSLTM (time-aware LSTM), B=64 T=512 D=256 H=512 — round 3: MFMA.
// Persistent kernel: 256 blocks x 512 threads (8 waves), 1 block/CU.
// Grid: 4 batch-groups (16 batches) x 64 col-slices (8 h-cols = 32 gate cols).
// Per step per block:
//   gates[16][32] = [h|x](16x768)bf16 @ [U;W](768x32)bf16   (MFMA 16x16x32)
//   s[16][8]      = c(16x512)bf16 @ Wd(512x8)bf16           (MFMA 16x16x32)
// Weights live in VGPRs (preloaded once, bf16 B-fragments). h/c exchanged
// across blocks as bf16 via d_ws; c carried in f32 REGISTERS of cell threads
// (exact f32 recurrence, zero c-exchange precision loss for the carry path).
// Barrier: proven r2 flag design (release store + lane-parallel poll + acquire
// fence, agent scope), groups of 64 blocks (bid mod 4).
// ---------------------------------------------------------------------------

constexpr int kB = 64, kT = 512, kD = 256, kH = 512, kG = 2048;
constexpr int NBLK = 256, NTHR = 512;
constexpr int BPG  = 16;   // batches per group

typedef __attribute__((ext_vector_type(8))) short short8v;  // 8 bf16
typedef __attribute__((ext_vector_type(4))) float f32x4;

__device__ __forceinline__ float fsig(float x)  { return 1.0f / (1.0f + __expf(-x)); }
__device__ __forceinline__ float ftanh(float x) { return 2.0f / (1.0f + __expf(-2.0f * x)) - 1.0f; }
__device__ __forceinline__ unsigned short f2bf(float f) {   // RNE f32->bf16
  unsigned u = __float_as_uint(f);
  return (unsigned short)((u + 0x7FFFu + ((u >> 16) & 1u)) >> 16);
}

__global__ __launch_bounds__(NTHR, 2) void mtsltm_kernel(
    const float* __restrict__ inp, const float* __restrict__ tdel,
    const float* __restrict__ Wd,  const float* __restrict__ W,
    const float* __restrict__ U,   const float* __restrict__ bias,
    float* __restrict__ out,
    unsigned short* __restrict__ hbf, unsigned short* __restrict__ cbf,
    unsigned* __restrict__ flags)
{
  // LDS (60.5 KB): padded rows -> 2-way-max bank aliasing on A-fragment reads.
  __shared__ unsigned short hx[16][776];   // [h(512) | x(256)] bf16, pad 8
  __shared__ unsigned short cb[16][536];   // c bf16, pad 24 (67*16B stride)
  __shared__ float g_part[8][64][4];       // per-wave gate MFMA partials
  __shared__ float s_part[8][64][4];       // per-wave Wd MFMA partials
  __shared__ float g_full[16][33];         // summed gate pre-activations
  __shared__ float td_s[16];

  const int tid = threadIdx.x, bid = blockIdx.x;
  const int bg = bid & 3;          // batch group (64-block sync group)
  const int cs = bid >> 2;         // col slice [0,64): h-cols cs*8..cs*8+8
  const int wv = tid >> 6, ln = tid & 63;
  const int lm = ln & 15, lg = ln >> 4;   // MFMA: row/col = lane&15, k-group = lane>>4
  const int kq = wv >> 1, nh = wv & 1;    // gates: wave = (k-quarter, n-half)

  // ---------------- one-time: weights -> VGPRs (bf16 B-fragments) -----------
  short8v bU[6];
  {
    const int c  = nh * 16 + lm;                       // local gate col 0..31
    const int gc = (c >> 3) * kH + cs * 8 + (c & 7);   // global gate col
    #pragma unroll
    for (int kt = 0; kt < 6; ++kt) {
      short8v v;
      #pragma unroll
      for (int e = 0; e < 8; ++e) {
        int k = kq * 192 + kt * 32 + lg * 8 + e;       // same (g,e)->k map as A
        float f = (k < kH) ? U[(size_t)k * kG + gc] : W[(size_t)(k - kH) * kG + gc];
        v[e] = (short)f2bf(f);
      }
      bU[kt] = v;
    }
  }
  short8v bWd[2];
  {
    #pragma unroll
    for (int kt = 0; kt < 2; ++kt) {
      short8v v;
      #pragma unroll
      for (int e = 0; e < 8; ++e) {
        int k = wv * 64 + kt * 32 + lg * 8 + e;
        float f = (lm < 8) ? Wd[(size_t)k * kH + cs * 8 + lm] : 0.0f;
        v[e] = (short)f2bf(f);
      }
      bWd[kt] = v;
    }
  }
  const int sm = tid >> 5, sc = tid & 31;                       // sum-stage id
  const float bias_r = bias[(sc >> 3) * kH + cs * 8 + (sc & 7)];
  const int cm = tid >> 3, cjj = tid & 7;                       // cell id (tid<128)
  float c_keep = 0.0f;                                          // f32 cell carry

  const int r = tid & 15, ch = tid >> 4;                        // staging id
  const int bgl_r = bg * BPG + r;
  const size_t HID = (size_t)kB * kT * kH;

  for (int t = 0; t < kT; ++t) {
    // ---------------- stage h, c (bf16 exchange), x, td into LDS ------------
    if (t == 0) {
      short8v z = {0,0,0,0,0,0,0,0};
      *(short8v*)&hx[r][ch * 16]     = z;
      *(short8v*)&hx[r][ch * 16 + 8] = z;
      *(short8v*)&cb[r][ch * 16]     = z;
      *(short8v*)&cb[r][ch * 16 + 8] = z;
    } else {
      const unsigned short* hs = hbf + ((size_t)((t - 1) & 1) * kB + bgl_r) * kH + ch * 16;
      short8v h0 = *(const short8v*)hs, h1 = *(const short8v*)(hs + 8);
      *(short8v*)&hx[r][ch * 16]     = h0;
      *(short8v*)&hx[r][ch * 16 + 8] = h1;
      const unsigned short* csrc = cbf + ((size_t)((t - 1) & 1) * kB + bgl_r) * kH + ch * 16;
      short8v c0 = *(const short8v*)csrc, c1 = *(const short8v*)(csrc + 8);
      *(short8v*)&cb[r][ch * 16]     = c0;
      *(short8v*)&cb[r][ch * 16 + 8] = c1;
    }
    {
      const float* xs = inp + ((size_t)bgl_r * kT + t) * kD + ch * 8;
      float4 x0 = *(const float4*)xs, x1 = *(const float4*)(xs + 4);
      short8v xv;
      xv[0] = f2bf(x0.x); xv[1] = f2bf(x0.y); xv[2] = f2bf(x0.z); xv[3] = f2bf(x0.w);
      xv[4] = f2bf(x1.x); xv[5] = f2bf(x1.y); xv[6] = f2bf(x1.z); xv[7] = f2bf(x1.w);
      *(short8v*)&hx[r][512 + ch * 8] = xv;
    }
    if (tid < BPG) td_s[tid] = tdel[(size_t)(bg * BPG + tid) * kT + t];
    __syncthreads();

    // ---------------- gates GEMM: wave = (kq, nh), 6 k-tiles ----------------
    {
      f32x4 acc = {0.f, 0.f, 0.f, 0.f};
      #pragma unroll
      for (int kt = 0; kt < 6; ++kt) {
        int kb = kq * 192 + kt * 32 + lg * 8;
        short8v a = *(const short8v*)&hx[lm][kb];
        acc = __builtin_amdgcn_mfma_f32_16x16x32_bf16(a, bU[kt], acc, 0, 0, 0);
      }
      *(f32x4*)&g_part[wv][ln][0] = acc;
    }
    // ---------------- Wd GEMM: wave = k-eighth, 2 k-tiles -------------------
    {
      f32x4 acc = {0.f, 0.f, 0.f, 0.f};
      #pragma unroll
      for (int kt = 0; kt < 2; ++kt) {
        int kb = wv * 64 + kt * 32 + lg * 8;
        short8v a = *(const short8v*)&cb[lm][kb];
        acc = __builtin_amdgcn_mfma_f32_16x16x32_bf16(a, bWd[kt], acc, 0, 0, 0);
      }
      *(f32x4*)&s_part[wv][ln][0] = acc;
    }
    __syncthreads();

    // ---------------- sum gate partials (+bias) -> g_full -------------------
    {
      // D layout (m89): row m=(lane>>4)*4+j, col n=lane&15.
      int lidx = ((sm >> 2) << 4) + (sc & 15);
      int j = sm & 3, nh2 = sc >> 4;
      float s = bias_r;
      #pragma unroll
      for (int q = 0; q < 4; ++q) s += g_part[q * 2 + nh2][lidx][j];
      g_full[sm][sc] = s;
    }
    __syncthreads();

    // ---------------- cell update (128 threads, f32 carry) ------------------
    if (tid < BPG * 8) {
      float sw = 0.f;
      int lidx = ((cm >> 2) << 4) + cjj, j = cm & 3;
      #pragma unroll
      for (int w = 0; w < 8; ++w) sw += s_part[w][lidx][j];
      float csv  = ftanh(sw);
      float td   = td_s[cm];
      float cadj = (c_keep - csv) + csv / __logf(2.71828182845904523536f + td);
      float gi = fsig (g_full[cm][cjj]);
      float gf = fsig (g_full[cm][8 + cjj]);
      float gg = ftanh(g_full[cm][16 + cjj]);
      float go = fsig (g_full[cm][24 + cjj]);
      float cnew = fmaf(gf, cadj, gi * gg);
      float tcn  = ftanh(cnew);          // = c_out
      float hout = ftanh(go * tcn);      // = tanh(o * tanh(c_new))
      c_keep = tcn;
      int col = cs * 8 + cjj;
      size_t bgl = (size_t)bg * BPG + cm;
      out[(bgl * kT + t) * kH + col] = hout;
      hbf[((size_t)(t & 1) * kB + bgl) * kH + col] = f2bf(hout);
      cbf[((size_t)(t & 1) * kB + bgl) * kH + col] = f2bf(tcn);
      if (t == kT - 1) {
        out[HID + bgl * kH + col] = hout;                      // h_t
        out[HID + (size_t)kB * kH + bgl * kH + col] = tcn;     // c_t
      }
    }

    // ---------------- 64-block group barrier (r2-proven design) -------------
    __syncthreads();   // drain all waves' stores before release
    if (tid == 0)
      __hip_atomic_store(&flags[bid * 32], (unsigned)(t + 1),
                         __ATOMIC_RELEASE, __HIP_MEMORY_SCOPE_AGENT);
    if (wv == 0) {
      const int member = (ln * 4 + bg) * 32;   // 64 members, 128 B apart
      int spins = 0;
      for (;;) {
        unsigned v = __hip_atomic_load(&flags[member], __ATOMIC_RELAXED,
                                       __HIP_MEMORY_SCOPE_AGENT);
        if (__all(v >= (unsigned)(t + 1))) break;
        if (++spins > (1 << 20)) break;   // safety valve
      }
      __builtin_amdgcn_fence(__ATOMIC_ACQUIRE, "agent");
    }
    __syncthreads();
  }
}

extern "C" void kernel_launch(void* const* d_in, const int* in_sizes, int n_in,
                              void* d_out, int out_size, void* d_ws, size_t ws_size,
                              hipStream_t stream)
{
  const float* inp  = (const float*)d_in[0];
  const float* td   = (const float*)d_in[1];
  const float* Wd   = (const float*)d_in[2];
  const float* W    = (const float*)d_in[3];
  const float* U    = (const float*)d_in[4];
  const float* bias = (const float*)d_in[5];
  float* out = (float*)d_out;

  // ws: hbf[2][64][512] bf16 (128KB) | cbf[2][64][512] bf16 (128KB) | flags (32KB)
  unsigned short* hbf = (unsigned short*)d_ws;
  unsigned short* cbf = hbf + (size_t)2 * kB * kH;
  unsigned* flags = (unsigned*)((char*)d_ws + (size_t)4 * kB * kH * sizeof(unsigned short));

  hipMemsetAsync(flags, 0, NBLK * 32 * sizeof(unsigned), stream);
  mtsltm_kernel<<<dim3(NBLK), dim3(NTHR), 0, stream>>>(inp, td, Wd, W, U, bias,
                                                       out, hbf, cbf, flags);
}

// Round 4
// 2937.530 us; speedup vs baseline: 6.5373x; 1.6991x over previous
//
#include <hip/hip_runtime.h>

// ---------------------------------------------------------------------------
// MTSLTM (time-aware LSTM), B=64 T=512 D=256 H=512 — round 4: fence-free sync.
// Persistent kernel: 128 blocks x 512 threads (8 waves), 1 block/CU.
// Grid: 4 batch-groups (16 batches) x 32 col-slices (16 h-cols = 64 gate cols).
// Per step per block:
//   gates[16][64] = [h|x](16x768)bf16 @ [U;W](768x64)bf16   (MFMA 16x16x32)
//   s[16][16]     = c(16x512)bf16 @ Wd(512x16)bf16          (MFMA 16x16x32)
// Weights in VGPRs (bf16 B-frags, preloaded once). c carried in f32 registers.
// Cross-block h/c exchange + flags use RELAXED AGENT-SCOPE ATOMICS ONLY
// (sc1 loads/stores: bypass L1/L2, coherent at L3) -> no wbl2/inv fences.
// Ordering: __syncthreads' vmcnt(0) drain before the flag store; readers'
// sc1 loads issue after the poll load is branched on (in-order issue).
// LDS staging uses a 16B-unit XOR swizzle (u ^= row&7) -> conflict-free.
// ---------------------------------------------------------------------------

constexpr int kB = 64, kT = 512, kD = 256, kH = 512, kG = 2048;
constexpr int NBLK = 128, NTHR = 512;
constexpr int BPG  = 16;   // batches per group

typedef __attribute__((ext_vector_type(8))) short short8v;  // 8 bf16
typedef __attribute__((ext_vector_type(4))) float f32x4;

__device__ __forceinline__ float fsig(float x)  { return 1.0f / (1.0f + __expf(-x)); }
__device__ __forceinline__ float ftanh(float x) { return 2.0f / (1.0f + __expf(-2.0f * x)) - 1.0f; }
__device__ __forceinline__ unsigned short f2bf(float f) {   // RNE f32->bf16
  unsigned u = __float_as_uint(f);
  return (unsigned short)((u + 0x7FFFu + ((u >> 16) & 1u)) >> 16);
}
__device__ __forceinline__ unsigned pk2(float a, float b) {
  return (unsigned)f2bf(a) | ((unsigned)f2bf(b) << 16);
}

__global__ __launch_bounds__(NTHR, 2) void mtsltm_kernel(
    const float* __restrict__ inp, const float* __restrict__ tdel,
    const float* __restrict__ Wd,  const float* __restrict__ W,
    const float* __restrict__ U,   const float* __restrict__ bias,
    float* __restrict__ out,
    unsigned* __restrict__ hbf, unsigned* __restrict__ cbf,
    unsigned* __restrict__ flags)
{
  // 56 KB LDS, all XOR-swizzled in 16B units: unit' = unit ^ (row & 7).
  __shared__ __align__(16) unsigned short hx[16][768];   // [h(512)|x(256)] bf16, 24 KB
  __shared__ __align__(16) unsigned short cbt[16][512];  // c bf16, 16 KB
  __shared__ __align__(16) float g_part[8][64][4];       // gate MFMA partials, 8 KB
  __shared__ __align__(16) float s_part[8][64][4];       // Wd MFMA partials, 8 KB

  const int tid = threadIdx.x, bid = blockIdx.x;
  const int bg = bid & 3;          // batch group (32-block sync group)
  const int cs = bid >> 2;         // col slice [0,32): h-cols cs*16..cs*16+16
  const int wv = tid >> 6, ln = tid & 63;
  const int lm = ln & 15, lg = ln >> 4;   // MFMA lane decomposition
  const int ct = wv >> 1, kh = wv & 1;    // gates: wave = (gate ct, k-half kh)

  // ---------------- one-time: weights -> VGPRs (bf16 B-fragments) -----------
  short8v bU[12];
  {
    const int gc = ct * kH + cs * 16 + lm;      // global gate col (gate=ct)
    #pragma unroll
    for (int kt = 0; kt < 12; ++kt) {
      short8v v;
      #pragma unroll
      for (int e = 0; e < 8; ++e) {
        int k = kh * 384 + kt * 32 + lg * 8 + e;     // same (lg,e)->k map as A
        float f = (k < kH) ? U[(size_t)k * kG + gc] : W[(size_t)(k - kH) * kG + gc];
        v[e] = (short)f2bf(f);
      }
      bU[kt] = v;
    }
  }
  short8v bWd2[2];
  {
    #pragma unroll
    for (int kt = 0; kt < 2; ++kt) {
      short8v v;
      #pragma unroll
      for (int e = 0; e < 8; ++e) {
        int k = wv * 64 + kt * 32 + lg * 8 + e;
        v[e] = (short)f2bf(Wd[(size_t)k * kH + cs * 16 + lm]);
      }
      bWd2[kt] = v;
    }
  }

  // ---------------- cell-thread identity (tid < 256) ----------------
  const int cm = tid >> 4, cj = tid & 15;
  float bias_r[4];
  #pragma unroll
  for (int g = 0; g < 4; ++g) bias_r[g] = bias[g * kH + cs * 16 + cj];
  float c_keep = 0.0f;                          // exact f32 cell carry
  const size_t bglc = (size_t)bg * BPG + (cm & 15);

  // ---------------- staging identity ----------------
  const int r = tid & 15, ch = tid >> 4;        // row (batch) r, chunk ch in [0,32)
  const int rs = r & 7;
  const int bgl_r = bg * BPG + r;
  const size_t HID = (size_t)kB * kT * kH;

  // x prefetch registers (for step t, loaded during previous step's poll)
  float4 xa = *(const float4*)(inp + ((size_t)bgl_r * kT) * kD + ch * 8);
  float4 xb = *(const float4*)(inp + ((size_t)bgl_r * kT) * kD + ch * 8 + 4);

  for (int t = 0; t < kT; ++t) {
    // ---------------- stage h, c (sc1 atomic loads), x into LDS -------------
    if (t == 0) {
      uint4 z = {0u, 0u, 0u, 0u};
      *(uint4*)&hx [r][((2 * ch)     ^ rs) * 8] = z;
      *(uint4*)&hx [r][((2 * ch + 1) ^ rs) * 8] = z;
      *(uint4*)&cbt[r][((2 * ch)     ^ rs) * 8] = z;
      *(uint4*)&cbt[r][((2 * ch + 1) ^ rs) * 8] = z;
    } else {
      const unsigned* hs = hbf + ((size_t)((t - 1) & 1) * kB + bgl_r) * 256 + ch * 8;
      const unsigned* cr = cbf + ((size_t)((t - 1) & 1) * kB + bgl_r) * 256 + ch * 8;
      unsigned hv[8], cv[8];
      #pragma unroll
      for (int i = 0; i < 8; ++i)
        hv[i] = __hip_atomic_load(hs + i, __ATOMIC_RELAXED, __HIP_MEMORY_SCOPE_AGENT);
      #pragma unroll
      for (int i = 0; i < 8; ++i)
        cv[i] = __hip_atomic_load(cr + i, __ATOMIC_RELAXED, __HIP_MEMORY_SCOPE_AGENT);
      uint4 a0, a1, b0, b1;
      a0.x = hv[0]; a0.y = hv[1]; a0.z = hv[2]; a0.w = hv[3];
      a1.x = hv[4]; a1.y = hv[5]; a1.z = hv[6]; a1.w = hv[7];
      b0.x = cv[0]; b0.y = cv[1]; b0.z = cv[2]; b0.w = cv[3];
      b1.x = cv[4]; b1.y = cv[5]; b1.z = cv[6]; b1.w = cv[7];
      *(uint4*)&hx [r][((2 * ch)     ^ rs) * 8] = a0;
      *(uint4*)&hx [r][((2 * ch + 1) ^ rs) * 8] = a1;
      *(uint4*)&cbt[r][((2 * ch)     ^ rs) * 8] = b0;
      *(uint4*)&cbt[r][((2 * ch + 1) ^ rs) * 8] = b1;
    }
    {
      uint4 xv;
      xv.x = pk2(xa.x, xa.y); xv.y = pk2(xa.z, xa.w);
      xv.z = pk2(xb.x, xb.y); xv.w = pk2(xb.z, xb.w);
      *(uint4*)&hx[r][((64 + ch) ^ rs) * 8] = xv;
    }
    __syncthreads();

    // ---------------- gates GEMM: wave = (ct, kh), 12 k-tiles ---------------
    {
      f32x4 acc = {0.f, 0.f, 0.f, 0.f};
      #pragma unroll
      for (int kt = 0; kt < 12; ++kt) {
        int u = kh * 48 + kt * 4 + lg;
        short8v a = *(const short8v*)&hx[lm][(u ^ (lm & 7)) * 8];
        acc = __builtin_amdgcn_mfma_f32_16x16x32_bf16(a, bU[kt], acc, 0, 0, 0);
      }
      *(f32x4*)&g_part[wv][ln][0] = acc;
    }
    // ---------------- Wd GEMM: wave = k-eighth, 2 k-tiles -------------------
    {
      f32x4 aw = {0.f, 0.f, 0.f, 0.f};
      #pragma unroll
      for (int kt = 0; kt < 2; ++kt) {
        int u = wv * 8 + kt * 4 + lg;
        short8v a = *(const short8v*)&cbt[lm][(u ^ (lm & 7)) * 8];
        aw = __builtin_amdgcn_mfma_f32_16x16x32_bf16(a, bWd2[kt], aw, 0, 0, 0);
      }
      *(f32x4*)&s_part[wv][ln][0] = aw;
    }
    __syncthreads();

    // ---------------- cell update (256 threads, f32 carry) ------------------
    if (tid < 256) {
      // D layout (m89): row m = (lane>>4)*4 + reg, col n = lane&15.
      int lidx = ((cm >> 2) << 4) | cj, jr = cm & 3;
      float g0 = bias_r[0] + g_part[0][lidx][jr] + g_part[1][lidx][jr];
      float g1 = bias_r[1] + g_part[2][lidx][jr] + g_part[3][lidx][jr];
      float g2 = bias_r[2] + g_part[4][lidx][jr] + g_part[5][lidx][jr];
      float g3 = bias_r[3] + g_part[6][lidx][jr] + g_part[7][lidx][jr];
      float sw = 0.f;
      #pragma unroll
      for (int w = 0; w < 8; ++w) sw += s_part[w][lidx][jr];
      float csv  = ftanh(sw);
      float td   = tdel[bglc * kT + t];
      float cadj = (c_keep - csv) + csv / __logf(2.71828182845904523536f + td);
      float gi = fsig(g0), gf = fsig(g1), gg = ftanh(g2), go = fsig(g3);
      float cnew = fmaf(gf, cadj, gi * gg);
      float tcn  = ftanh(cnew);          // = c_out
      float hout = ftanh(go * tcn);      // = tanh(o * tanh(c_new))
      c_keep = tcn;
      int col = cs * 16 + cj;
      out[(bglc * kT + t) * kH + col] = hout;
      float h2 = __shfl_xor(hout, 1), c2 = __shfl_xor(tcn, 1);
      if (!(cj & 1)) {
        unsigned hp = pk2(hout, h2), cp = pk2(tcn, c2);
        size_t di = ((size_t)(t & 1) * kB + bglc) * 256 + (col >> 1);
        __hip_atomic_store(hbf + di, hp, __ATOMIC_RELAXED, __HIP_MEMORY_SCOPE_AGENT);
        __hip_atomic_store(cbf + di, cp, __ATOMIC_RELAXED, __HIP_MEMORY_SCOPE_AGENT);
      }
      if (t == kT - 1) {
        out[HID + bglc * kH + col] = hout;                      // h_t
        out[HID + (size_t)kB * kH + bglc * kH + col] = tcn;     // c_t
      }
    }

    // ---------------- fence-free group barrier ------------------------------
    // __syncthreads emits s_waitcnt vmcnt(0) per wave -> all sc1 stores are at
    // the coherence point before any wave passes; then post our flag.
    __syncthreads();
    if (tid == 0)
      __hip_atomic_store(&flags[bid * 32], (unsigned)(t + 1),
                         __ATOMIC_RELAXED, __HIP_MEMORY_SCOPE_AGENT);
    // prefetch next x while polling (normal cached loads, drain at final sync)
    if (t + 1 < kT) {
      const float* xs = inp + ((size_t)bgl_r * kT + (t + 1)) * kD + ch * 8;
      xa = *(const float4*)xs;
      xb = *(const float4*)(xs + 4);
    }
    if (wv == 0) {
      const int member = ((ln & 31) * 4 + bg) * 32;   // 32 members, 128 B apart
      int spins = 0;
      for (;;) {
        unsigned v = (ln < 32)
            ? __hip_atomic_load(&flags[member], __ATOMIC_RELAXED, __HIP_MEMORY_SCOPE_AGENT)
            : 0xFFFFFFFFu;
        if (__all(v >= (unsigned)(t + 1))) break;
        if (++spins > (1 << 20)) break;   // safety valve
      }
      __atomic_signal_fence(__ATOMIC_ACQUIRE);  // compiler ordering only
    }
    __syncthreads();
  }
}

extern "C" void kernel_launch(void* const* d_in, const int* in_sizes, int n_in,
                              void* d_out, int out_size, void* d_ws, size_t ws_size,
                              hipStream_t stream)
{
  const float* inp  = (const float*)d_in[0];
  const float* td   = (const float*)d_in[1];
  const float* Wd   = (const float*)d_in[2];
  const float* W    = (const float*)d_in[3];
  const float* U    = (const float*)d_in[4];
  const float* bias = (const float*)d_in[5];
  float* out = (float*)d_out;

  // ws: hbf[2][64][256] uint (128KB) | cbf[2][64][256] uint (128KB) | flags 16KB
  unsigned* hbf   = (unsigned*)d_ws;
  unsigned* cbf   = hbf + (size_t)2 * kB * 256;
  unsigned* flags = cbf + (size_t)2 * kB * 256;

  hipMemsetAsync(flags, 0, NBLK * 32 * sizeof(unsigned), stream);
  mtsltm_kernel<<<dim3(NBLK), dim3(NTHR), 0, stream>>>(inp, td, Wd, W, U, bias,
                                                       out, hbf, cbf, flags);
}

// Round 5
// 2012.464 us; speedup vs baseline: 9.5422x; 1.4597x over previous
//
#include <hip/hip_runtime.h>

// ---------------------------------------------------------------------------
// MTSLTM (time-aware LSTM), B=64 T=512 D=256 H=512 — round 5.
// Persistent kernel: 64 blocks x 512 threads (8 waves), 1 block/CU.
// Grid: 4 batch-groups (16 batches) x 16 col-slices (32 h-cols = 128 g-cols).
// Serial chain per step: {h/c sc1-exchange -> h@U + c@Wd MFMA -> cell}.
// x@W (K=256) for step t+1 is computed via MFMA DURING the poll window and
// fed as the C-input of t+1's h@U GEMM. x[t+2] prefetched to regs.
// Exchange: relaxed agent-scope (sc1) ops only — fence-free (r4-validated).
// Stage loads widened to global_load_dwordx4 sc1 via inline asm.
// ---------------------------------------------------------------------------

constexpr int kB = 64, kT = 512, kD = 256, kH = 512, kG = 2048;
constexpr int NBLK = 64, NTHR = 512;
constexpr int BPG  = 16;   // batches per group

typedef __attribute__((ext_vector_type(8))) short short8v;   // 8 bf16
typedef __attribute__((ext_vector_type(4))) float f32x4;
typedef __attribute__((ext_vector_type(4))) unsigned int uint4v;

__device__ __forceinline__ float fsig(float x)  { return 1.0f / (1.0f + __expf(-x)); }
__device__ __forceinline__ float ftanh(float x) { return 2.0f / (1.0f + __expf(-2.0f * x)) - 1.0f; }
__device__ __forceinline__ unsigned short f2bf(float f) {    // RNE f32->bf16
  unsigned u = __float_as_uint(f);
  return (unsigned short)((u + 0x7FFFu + ((u >> 16) & 1u)) >> 16);
}
__device__ __forceinline__ unsigned pk2(float a, float b) {
  return (unsigned)f2bf(a) | ((unsigned)f2bf(b) << 16);
}

__global__ __launch_bounds__(NTHR, 2) void mtsltm_kernel(
    const float* __restrict__ inp, const float* __restrict__ tdel,
    const float* __restrict__ Wd,  const float* __restrict__ W,
    const float* __restrict__ U,   const float* __restrict__ bias,
    float* __restrict__ out,
    unsigned* __restrict__ hb32, unsigned* __restrict__ cb32,
    unsigned* __restrict__ flags)
{
  // 56.1 KB LDS. h/c/x are XOR-swizzled in 16B units: unit' = unit ^ (row&7).
  __shared__ __align__(16) unsigned short h_lds[16][512];  // 16 KB
  __shared__ __align__(16) unsigned short c_lds[16][512];  // 16 KB
  __shared__ __align__(16) unsigned short x_lds[16][256];  // 8 KB
  __shared__ __align__(16) float g_full[8][64][4];         // 8 KB gate preacts
  __shared__ __align__(16) float s_part[8][64][4];         // 8 KB Wd partials

  const int tid = threadIdx.x, bid = blockIdx.x;
  const int bg = bid & 3;          // batch group (16-block sync group)
  const int cs = bid >> 2;         // col slice [0,16): h-cols cs*32..cs*32+32
  const int wv = tid >> 6, ln = tid & 63;
  const int lm = ln & 15, lg = ln >> 4;   // MFMA lane decomposition

  // ---------------- one-time: weights -> VGPRs (bf16 B-fragments) -----------
  // gates: wave wv = n-tile: gate = wv>>1, h-col half = wv&1.
  const int gcol = (wv >> 1) * kH + cs * 32 + (wv & 1) * 16 + lm;
  short8v bU[16];                                   // U[512][gcol]  (64 VGPR)
  #pragma unroll
  for (int kt = 0; kt < 16; ++kt) {
    short8v v;
    #pragma unroll
    for (int e = 0; e < 8; ++e)
      v[e] = (short)f2bf(U[(size_t)(kt * 32 + lg * 8 + e) * kG + gcol]);
    bU[kt] = v;
  }
  short8v bX[8];                                    // W[256][gcol]  (32 VGPR)
  #pragma unroll
  for (int kt = 0; kt < 8; ++kt) {
    short8v v;
    #pragma unroll
    for (int e = 0; e < 8; ++e)
      v[e] = (short)f2bf(W[(size_t)(kt * 32 + lg * 8 + e) * kG + gcol]);
    bX[kt] = v;
  }
  // Wd: wave = (kq = wv>>1, ns = wv&1): cols cs*32+ns*16+lm, k-quarter kq.
  const int kq = wv >> 1, ns = wv & 1;
  short8v bWd[4];                                   // (16 VGPR)
  #pragma unroll
  for (int kt = 0; kt < 4; ++kt) {
    short8v v;
    #pragma unroll
    for (int e = 0; e < 8; ++e)
      v[e] = (short)f2bf(Wd[(size_t)(kq * 128 + kt * 32 + lg * 8 + e) * kH
                            + cs * 32 + ns * 16 + lm]);
    bWd[kt] = v;
  }
  const float bias_r = bias[gcol];

  // ---------------- identities ----------------
  const int r = tid & 15, ch = tid >> 4, rs = r & 7;   // staging: batch r, chunk ch
  const int bgl_r = bg * BPG + r;
  const int cm = tid >> 5, cj = tid & 31;              // cell: batch cm, col cj
  const int lidx = ((cm >> 2) << 4) | (cj & 15), jr = cm & 3, chf = cj >> 4;
  const size_t bglc = (size_t)bg * BPG + cm;
  const int colg = cs * 32 + cj;
  float c_keep = 0.0f;                                 // exact f32 cell carry
  const size_t HID = (size_t)kB * kT * kH;

  auto xgemm = [&]() -> f32x4 {    // x-part of next step's gates (+bias)
    f32x4 a = {bias_r, bias_r, bias_r, bias_r};
    #pragma unroll
    for (int kt = 0; kt < 8; ++kt) {
      short8v av = *(const short8v*)&x_lds[lm][((kt * 4 + lg) ^ (lm & 7)) * 8];
      a = __builtin_amdgcn_mfma_f32_16x16x32_bf16(av, bX[kt], a, 0, 0, 0);
    }
    return a;
  };

  // ---------------- prologue: stage x[0], prefetch x[1], xacc for t=0 -------
  {
    const float* xs = inp + ((size_t)bgl_r * kT + 0) * kD + ch * 8;
    float4 a = *(const float4*)xs, b = *(const float4*)(xs + 4);
    uint4v xv;
    xv.x = pk2(a.x, a.y); xv.y = pk2(a.z, a.w);
    xv.z = pk2(b.x, b.y); xv.w = pk2(b.z, b.w);
    *(uint4v*)&x_lds[r][(ch ^ rs) * 8] = xv;
  }
  float4 xa, xb;
  {
    const float* xs = inp + ((size_t)bgl_r * kT + 1) * kD + ch * 8;
    xa = *(const float4*)xs; xb = *(const float4*)(xs + 4);
  }
  __syncthreads();
  f32x4 xacc = xgemm();
  __syncthreads();   // protect x_lds before t=0's overwrite

  for (int t = 0; t < kT; ++t) {
    const float tdv = tdel[bglc * kT + t];   // issued early, used in cell

    // ---------------- stage h, c (dwordx4 sc1) and x[t+1] into LDS ----------
    if (t > 0) {
      const unsigned* hsrc = hb32 + ((size_t)((t - 1) & 1) * kB + bgl_r) * 256 + ch * 8;
      const unsigned* csrc = cb32 + ((size_t)((t - 1) & 1) * kB + bgl_r) * 256 + ch * 8;
      uint4v h0, h1, c0, c1;
      asm volatile(
        "global_load_dwordx4 %0, %4, off sc1\n\t"
        "global_load_dwordx4 %1, %4, off offset:16 sc1\n\t"
        "global_load_dwordx4 %2, %5, off sc1\n\t"
        "global_load_dwordx4 %3, %5, off offset:16 sc1"
        : "=&v"(h0), "=&v"(h1), "=&v"(c0), "=&v"(c1)
        : "v"(hsrc), "v"(csrc));
      asm volatile("s_waitcnt vmcnt(0)" ::: "memory");
      __builtin_amdgcn_sched_barrier(0);
      *(uint4v*)&h_lds[r][((ch * 2)     ^ rs) * 8] = h0;
      *(uint4v*)&h_lds[r][((ch * 2 + 1) ^ rs) * 8] = h1;
      *(uint4v*)&c_lds[r][((ch * 2)     ^ rs) * 8] = c0;
      *(uint4v*)&c_lds[r][((ch * 2 + 1) ^ rs) * 8] = c1;
    }
    if (t + 1 < kT) {   // stage x[t+1] (from regs prefetched last step)
      uint4v xv;
      xv.x = pk2(xa.x, xa.y); xv.y = pk2(xa.z, xa.w);
      xv.z = pk2(xb.x, xb.y); xv.w = pk2(xb.z, xb.w);
      *(uint4v*)&x_lds[r][(ch ^ rs) * 8] = xv;
    }
    __syncthreads();                                   // sync1

    // ---------------- h@U (C-in = xacc) + c@Wd ------------------------------
    if (t > 0) {
      f32x4 a0 = xacc, a1 = {0.f, 0.f, 0.f, 0.f};
      #pragma unroll
      for (int kt = 0; kt < 8; ++kt) {
        short8v av = *(const short8v*)&h_lds[lm][((kt * 4 + lg) ^ (lm & 7)) * 8];
        a0 = __builtin_amdgcn_mfma_f32_16x16x32_bf16(av, bU[kt], a0, 0, 0, 0);
      }
      #pragma unroll
      for (int kt = 8; kt < 16; ++kt) {
        short8v av = *(const short8v*)&h_lds[lm][((kt * 4 + lg) ^ (lm & 7)) * 8];
        a1 = __builtin_amdgcn_mfma_f32_16x16x32_bf16(av, bU[kt], a1, 0, 0, 0);
      }
      f32x4 aw = {0.f, 0.f, 0.f, 0.f};
      #pragma unroll
      for (int kt = 0; kt < 4; ++kt) {
        short8v av = *(const short8v*)&c_lds[lm][((kq * 16 + kt * 4 + lg) ^ (lm & 7)) * 8];
        aw = __builtin_amdgcn_mfma_f32_16x16x32_bf16(av, bWd[kt], aw, 0, 0, 0);
      }
      *(f32x4*)&s_part[wv][ln][0] = aw;
      f32x4 g = a0 + a1;
      *(f32x4*)&g_full[wv][ln][0] = g;
    } else {
      *(f32x4*)&g_full[wv][ln][0] = xacc;   // h=0 at t=0 -> gates = xproj+bias
    }
    __syncthreads();                                   // sync2

    // ---------------- cell update (all 512 threads, f32 carry) --------------
    {
      float g0 = g_full[0 + chf][lidx][jr];
      float g1 = g_full[2 + chf][lidx][jr];
      float g2 = g_full[4 + chf][lidx][jr];
      float g3 = g_full[6 + chf][lidx][jr];
      float sw = 0.f;
      if (t > 0) {
        #pragma unroll
        for (int q = 0; q < 4; ++q) sw += s_part[2 * q + chf][lidx][jr];
      }
      float csv  = ftanh(sw);
      float cadj = (c_keep - csv) + csv / __logf(2.71828182845904523536f + tdv);
      float gi = fsig(g0), gf = fsig(g1), gg = ftanh(g2), go = fsig(g3);
      float cnew = fmaf(gf, cadj, gi * gg);
      float tcn  = ftanh(cnew);          // = c_out
      float hout = ftanh(go * tcn);      // = tanh(o * tanh(c_new))
      c_keep = tcn;
      out[(bglc * kT + t) * kH + colg] = hout;
      float h2 = __shfl_xor(hout, 1), c2 = __shfl_xor(tcn, 1);
      if (!(cj & 1)) {
        unsigned hp = pk2(hout, h2), cp = pk2(tcn, c2);
        size_t di = ((size_t)(t & 1) * kB + bglc) * 256 + (colg >> 1);
        __hip_atomic_store(hb32 + di, hp, __ATOMIC_RELAXED, __HIP_MEMORY_SCOPE_AGENT);
        __hip_atomic_store(cb32 + di, cp, __ATOMIC_RELAXED, __HIP_MEMORY_SCOPE_AGENT);
      }
      if (t == kT - 1) {
        out[HID + bglc * kH + colg] = hout;                      // h_t
        out[HID + (size_t)kB * kH + bglc * kH + colg] = tcn;     // c_t
      }
    }
    __syncthreads();   // sync3: drain all sc1 data stores before flag post

    if (tid == 0)
      __hip_atomic_store(&flags[bid * 32], (unsigned)(t + 1),
                         __ATOMIC_RELAXED, __HIP_MEMORY_SCOPE_AGENT);
    // ---------------- poll window: x-GEMM for t+1, x[t+2] prefetch ----------
    if (t + 1 < kT) xacc = xgemm();        // reads x_lds = x[t+1]
    if (t + 2 < kT) {
      const float* xs = inp + ((size_t)bgl_r * kT + (t + 2)) * kD + ch * 8;
      xa = *(const float4*)xs; xb = *(const float4*)(xs + 4);
    }
    if (wv == 0) {
      const int member = ((ln & 15) * 4 + bg) * 32;   // 16 members, 128 B apart
      int spins = 0;
      for (;;) {
        unsigned v = (ln < 16)
            ? __hip_atomic_load(&flags[member], __ATOMIC_RELAXED, __HIP_MEMORY_SCOPE_AGENT)
            : 0xFFFFFFFFu;
        if (__all(v >= (unsigned)(t + 1))) break;
        if (++spins > (1 << 20)) break;   // safety valve
      }
      __atomic_signal_fence(__ATOMIC_ACQUIRE);
    }
    __syncthreads();                                   // sync4 (barrier fan-out)
  }
}

extern "C" void kernel_launch(void* const* d_in, const int* in_sizes, int n_in,
                              void* d_out, int out_size, void* d_ws, size_t ws_size,
                              hipStream_t stream)
{
  const float* inp  = (const float*)d_in[0];
  const float* td   = (const float*)d_in[1];
  const float* Wd   = (const float*)d_in[2];
  const float* W    = (const float*)d_in[3];
  const float* U    = (const float*)d_in[4];
  const float* bias = (const float*)d_in[5];
  float* out = (float*)d_out;

  // ws: hb[2][64][512] bf16 (128KB) | cb same (128KB) | flags 64*32 uint (8KB)
  unsigned* hb32  = (unsigned*)d_ws;
  unsigned* cb32  = hb32 + (size_t)2 * kB * 256;
  unsigned* flags = cb32 + (size_t)2 * kB * 256;

  hipMemsetAsync(flags, 0, NBLK * 32 * sizeof(unsigned), stream);
  mtsltm_kernel<<<dim3(NBLK), dim3(NTHR), 0, stream>>>(inp, td, Wd, W, U, bias,
                                                       out, hb32, cb32, flags);
}

// Round 7
// 1821.071 us; speedup vs baseline: 10.5451x; 1.1051x over previous
//
#include <hip/hip_runtime.h>

// ---------------------------------------------------------------------------
// MTSLTM (time-aware LSTM), B=64 T=512 D=256 H=512 — round 6b (compile fix).
// Persistent kernel: 64 blocks x 512 threads (8 waves), 1 block/CU.
// Grid: 4 batch-groups (16 batches) x 16 col-slices (32 h-cols = 128 g-cols).
// Changes vs r5 (same math, same fence-free sc1 exchange protocol):
//  * per-wave poll: wave w polls producers {2w,2w+1} and immediately issues
//    their h/c sc1 dwordx4 loads -> parallel detection, pipelined loads.
//  * 3 syncthreads/step (poll replaces the tail barrier).
//  * out[] f32 stores moved AFTER the flag post (off the drained window) and
//    made non-temporal; inp loads non-temporal (stop evicting hb/cb from L3).
//  * tdel prefetched one step ahead.
// r6b: nontemporal builtins require clang vector types -> use ext_vector f32x4v.
// ---------------------------------------------------------------------------

constexpr int kB = 64, kT = 512, kD = 256, kH = 512, kG = 2048;
constexpr int NBLK = 64, NTHR = 512;
constexpr int BPG  = 16;   // batches per group

typedef __attribute__((ext_vector_type(8))) short short8v;   // 8 bf16
typedef __attribute__((ext_vector_type(4))) float f32x4;
typedef __attribute__((ext_vector_type(4))) float f32x4v;    // for NT builtins
typedef __attribute__((ext_vector_type(4))) unsigned int uint4v;

__device__ __forceinline__ float fsig(float x)  { return 1.0f / (1.0f + __expf(-x)); }
__device__ __forceinline__ float ftanh(float x) { return 2.0f / (1.0f + __expf(-2.0f * x)) - 1.0f; }
__device__ __forceinline__ unsigned short f2bf(float f) {    // RNE f32->bf16
  unsigned u = __float_as_uint(f);
  return (unsigned short)((u + 0x7FFFu + ((u >> 16) & 1u)) >> 16);
}
__device__ __forceinline__ unsigned pk2(float a, float b) {
  return (unsigned)f2bf(a) | ((unsigned)f2bf(b) << 16);
}

__global__ __launch_bounds__(NTHR, 2) void mtsltm_kernel(
    const float* __restrict__ inp, const float* __restrict__ tdel,
    const float* __restrict__ Wd,  const float* __restrict__ W,
    const float* __restrict__ U,   const float* __restrict__ bias,
    float* __restrict__ out,
    unsigned* __restrict__ hb32, unsigned* __restrict__ cb32,
    unsigned* __restrict__ flags)
{
  // 56.1 KB LDS. h/c/x are XOR-swizzled in 16B units: unit' = unit ^ (row&7).
  __shared__ __align__(16) unsigned short h_lds[16][512];  // 16 KB
  __shared__ __align__(16) unsigned short c_lds[16][512];  // 16 KB
  __shared__ __align__(16) unsigned short x_lds[16][256];  // 8 KB
  __shared__ __align__(16) float g_full[8][64][4];         // 8 KB gate preacts
  __shared__ __align__(16) float s_part[8][64][4];         // 8 KB Wd partials

  const int tid = threadIdx.x, bid = blockIdx.x;
  const int bg = bid & 3;          // batch group (16-block sync group)
  const int cs = bid >> 2;         // col slice [0,16): h-cols cs*32..cs*32+32
  const int wv = tid >> 6, ln = tid & 63;
  const int lm = ln & 15, lg = ln >> 4;   // MFMA lane decomposition

  // ---------------- one-time: weights -> VGPRs (bf16 B-fragments) -----------
  const int gcol = (wv >> 1) * kH + cs * 32 + (wv & 1) * 16 + lm;
  short8v bU[16];                                   // U[512][gcol]
  #pragma unroll
  for (int kt = 0; kt < 16; ++kt) {
    short8v v;
    #pragma unroll
    for (int e = 0; e < 8; ++e)
      v[e] = (short)f2bf(U[(size_t)(kt * 32 + lg * 8 + e) * kG + gcol]);
    bU[kt] = v;
  }
  short8v bX[8];                                    // W[256][gcol]
  #pragma unroll
  for (int kt = 0; kt < 8; ++kt) {
    short8v v;
    #pragma unroll
    for (int e = 0; e < 8; ++e)
      v[e] = (short)f2bf(W[(size_t)(kt * 32 + lg * 8 + e) * kG + gcol]);
    bX[kt] = v;
  }
  const int kq = wv >> 1, ns = wv & 1;
  short8v bWd[4];
  #pragma unroll
  for (int kt = 0; kt < 4; ++kt) {
    short8v v;
    #pragma unroll
    for (int e = 0; e < 8; ++e)
      v[e] = (short)f2bf(Wd[(size_t)(kq * 128 + kt * 32 + lg * 8 + e) * kH
                            + cs * 32 + ns * 16 + lm]);
    bWd[kt] = v;
  }
  const float bias_r = bias[gcol];

  // ---------------- identities ----------------
  const int r = tid & 15, ch = tid >> 4, rs = r & 7;   // x staging
  const int bgl_r = bg * BPG + r;
  const int row2 = ln >> 2, q = ln & 3;                // h/c staging (per wave)
  const int cm = tid >> 5, cj = tid & 31;              // cell: batch cm, col cj
  const int lidx = ((cm >> 2) << 4) | (cj & 15), jr = cm & 3, chf = cj >> 4;
  const size_t bglc = (size_t)bg * BPG + cm;
  const int colg = cs * 32 + cj;
  float c_keep = 0.0f;                                 // exact f32 cell carry
  const size_t HID = (size_t)kB * kT * kH;

  auto xgemm = [&]() -> f32x4 {    // x-part of next step's gates (+bias)
    f32x4 a = {bias_r, bias_r, bias_r, bias_r};
    #pragma unroll
    for (int kt = 0; kt < 8; ++kt) {
      short8v av = *(const short8v*)&x_lds[lm][((kt * 4 + lg) ^ (lm & 7)) * 8];
      a = __builtin_amdgcn_mfma_f32_16x16x32_bf16(av, bX[kt], a, 0, 0, 0);
    }
    return a;
  };

  // ---------------- prologue ----------------
  {  // zero h_lds, c_lds
    uint4v z = {0u, 0u, 0u, 0u};
    *(uint4v*)&((unsigned short*)h_lds)[tid * 16] = z;
    *(uint4v*)&((unsigned short*)h_lds)[tid * 16 + 8] = z;
    *(uint4v*)&((unsigned short*)c_lds)[tid * 16] = z;
    *(uint4v*)&((unsigned short*)c_lds)[tid * 16 + 8] = z;
  }
  {  // stage x[0]
    const float* xs = inp + ((size_t)bgl_r * kT + 0) * kD + ch * 8;
    f32x4v a = __builtin_nontemporal_load((const f32x4v*)xs);
    f32x4v b = __builtin_nontemporal_load((const f32x4v*)(xs + 4));
    uint4v xv;
    xv.x = pk2(a.x, a.y); xv.y = pk2(a.z, a.w);
    xv.z = pk2(b.x, b.y); xv.w = pk2(b.z, b.w);
    *(uint4v*)&x_lds[r][(ch ^ rs) * 8] = xv;
  }
  f32x4v xa, xb;
  {  // prefetch x[1]
    const float* xs = inp + ((size_t)bgl_r * kT + 1) * kD + ch * 8;
    xa = __builtin_nontemporal_load((const f32x4v*)xs);
    xb = __builtin_nontemporal_load((const f32x4v*)(xs + 4));
  }
  float tdv = tdel[bglc * kT + 0];
  __syncthreads();
  f32x4 xacc = xgemm();
  __syncthreads();   // protect x_lds before t=0's stage phase

  for (int t = 0; t < kT; ++t) {
    // ---------------- per-wave poll + h/c stage (sc1) -----------------------
    if (t > 0) {
      const unsigned* fp = flags + ((2 * wv + (ln & 1)) * 4 + bg) * 32;
      int spins = 0;
      for (;;) {
        unsigned v = (ln < 2)
            ? __hip_atomic_load(fp, __ATOMIC_RELAXED, __HIP_MEMORY_SCOPE_AGENT)
            : 0xFFFFFFFFu;
        if (__all(v >= (unsigned)t)) break;
        if (++spins > (1 << 20)) break;   // safety valve
      }
      __atomic_signal_fence(__ATOMIC_ACQUIRE);
      // load producers 2wv, 2wv+1: h/c chunks (16 rows x 32 cols each)
      const size_t rb = ((size_t)((t - 1) & 1) * kB + bg * 16 + row2) * 256
                        + (2 * wv) * 16 + q * 4;
      const unsigned* hsrc = hb32 + rb;
      const unsigned* csrc = cb32 + rb;
      uint4v h0, h1, c0, c1;
      asm volatile(
        "global_load_dwordx4 %0, %4, off sc1\n\t"
        "global_load_dwordx4 %1, %4, off offset:64 sc1\n\t"
        "global_load_dwordx4 %2, %5, off sc1\n\t"
        "global_load_dwordx4 %3, %5, off offset:64 sc1"
        : "=&v"(h0), "=&v"(h1), "=&v"(c0), "=&v"(c1)
        : "v"(hsrc), "v"(csrc));
      asm volatile("s_waitcnt vmcnt(0)" ::: "memory");
      __builtin_amdgcn_sched_barrier(0);
      const int rsw = row2 & 7;
      *(uint4v*)&h_lds[row2][((8 * wv + q)     ^ rsw) * 8] = h0;
      *(uint4v*)&h_lds[row2][((8 * wv + 4 + q) ^ rsw) * 8] = h1;
      *(uint4v*)&c_lds[row2][((8 * wv + q)     ^ rsw) * 8] = c0;
      *(uint4v*)&c_lds[row2][((8 * wv + 4 + q) ^ rsw) * 8] = c1;
    }
    if (t + 1 < kT) {   // stage x[t+1] from prefetched regs
      uint4v xv;
      xv.x = pk2(xa.x, xa.y); xv.y = pk2(xa.z, xa.w);
      xv.z = pk2(xb.x, xb.y); xv.w = pk2(xb.z, xb.w);
      *(uint4v*)&x_lds[r][(ch ^ rs) * 8] = xv;
    }
    __syncthreads();                                   // sync A

    // ---------------- h@U (C-in = xacc) + c@Wd ------------------------------
    if (t > 0) {
      f32x4 a0 = xacc, a1 = {0.f, 0.f, 0.f, 0.f};
      #pragma unroll
      for (int kt = 0; kt < 8; ++kt) {
        short8v av = *(const short8v*)&h_lds[lm][((kt * 4 + lg) ^ (lm & 7)) * 8];
        a0 = __builtin_amdgcn_mfma_f32_16x16x32_bf16(av, bU[kt], a0, 0, 0, 0);
      }
      #pragma unroll
      for (int kt = 8; kt < 16; ++kt) {
        short8v av = *(const short8v*)&h_lds[lm][((kt * 4 + lg) ^ (lm & 7)) * 8];
        a1 = __builtin_amdgcn_mfma_f32_16x16x32_bf16(av, bU[kt], a1, 0, 0, 0);
      }
      f32x4 aw = {0.f, 0.f, 0.f, 0.f};
      #pragma unroll
      for (int kt = 0; kt < 4; ++kt) {
        short8v av = *(const short8v*)&c_lds[lm][((kq * 16 + kt * 4 + lg) ^ (lm & 7)) * 8];
        aw = __builtin_amdgcn_mfma_f32_16x16x32_bf16(av, bWd[kt], aw, 0, 0, 0);
      }
      *(f32x4*)&s_part[wv][ln][0] = aw;
      f32x4 g = a0 + a1;
      *(f32x4*)&g_full[wv][ln][0] = g;
    } else {
      *(f32x4*)&g_full[wv][ln][0] = xacc;   // h=0 at t=0
    }
    __syncthreads();                                   // sync B

    // ---------------- cell update (all 512 threads, f32 carry) --------------
    float hout, tcn;
    {
      float g0 = g_full[0 + chf][lidx][jr];
      float g1 = g_full[2 + chf][lidx][jr];
      float g2 = g_full[4 + chf][lidx][jr];
      float g3 = g_full[6 + chf][lidx][jr];
      float sw = 0.f;
      if (t > 0) {
        #pragma unroll
        for (int q2 = 0; q2 < 4; ++q2) sw += s_part[2 * q2 + chf][lidx][jr];
      }
      float csv  = ftanh(sw);
      float cadj = (c_keep - csv) + csv / __logf(2.71828182845904523536f + tdv);
      float gi = fsig(g0), gf = fsig(g1), gg = ftanh(g2), go = fsig(g3);
      float cnew = fmaf(gf, cadj, gi * gg);
      tcn  = ftanh(cnew);                  // = c_out
      hout = ftanh(go * tcn);              // = tanh(o * tanh(c_new))
      c_keep = tcn;
      float h2 = __shfl_xor(hout, 1), c2 = __shfl_xor(tcn, 1);
      if (!(cj & 1)) {
        unsigned hp = pk2(hout, h2), cp = pk2(tcn, c2);
        size_t di = ((size_t)(t & 1) * kB + bglc) * 256 + (colg >> 1);
        __hip_atomic_store(hb32 + di, hp, __ATOMIC_RELAXED, __HIP_MEMORY_SCOPE_AGENT);
        __hip_atomic_store(cb32 + di, cp, __ATOMIC_RELAXED, __HIP_MEMORY_SCOPE_AGENT);
      }
    }
    // xgemm for t+1 (reads x_lds staged this step; must precede sync C)
    if (t + 1 < kT) xacc = xgemm();
    __syncthreads();   // sync C: drains sc1 h/c stores before flag post

    if (tid == 0)
      __hip_atomic_store(&flags[bid * 32], (unsigned)(t + 1),
                         __ATOMIC_RELAXED, __HIP_MEMORY_SCOPE_AGENT);

    // ---------------- shadow work (off the critical path) -------------------
    __builtin_nontemporal_store(hout, &out[(bglc * kT + t) * kH + colg]);
    if (t == kT - 1) {
      out[HID + bglc * kH + colg] = hout;                      // h_t
      out[HID + (size_t)kB * kH + bglc * kH + colg] = tcn;     // c_t
    }
    if (t + 2 < kT) {
      const float* xs = inp + ((size_t)bgl_r * kT + (t + 2)) * kD + ch * 8;
      xa = __builtin_nontemporal_load((const f32x4v*)xs);
      xb = __builtin_nontemporal_load((const f32x4v*)(xs + 4));
    }
    if (t + 1 < kT) tdv = tdel[bglc * kT + (t + 1)];
  }
}

extern "C" void kernel_launch(void* const* d_in, const int* in_sizes, int n_in,
                              void* d_out, int out_size, void* d_ws, size_t ws_size,
                              hipStream_t stream)
{
  const float* inp  = (const float*)d_in[0];
  const float* td   = (const float*)d_in[1];
  const float* Wd   = (const float*)d_in[2];
  const float* W    = (const float*)d_in[3];
  const float* U    = (const float*)d_in[4];
  const float* bias = (const float*)d_in[5];
  float* out = (float*)d_out;

  // ws: hb[2][64][512] bf16 (128KB) | cb same (128KB) | flags 64*32 uint (8KB)
  unsigned* hb32  = (unsigned*)d_ws;
  unsigned* cb32  = hb32 + (size_t)2 * kB * 256;
  unsigned* flags = cb32 + (size_t)2 * kB * 256;

  (void)hipMemsetAsync(flags, 0, NBLK * 32 * sizeof(unsigned), stream);
  mtsltm_kernel<<<dim3(NBLK), dim3(NTHR), 0, stream>>>(inp, td, Wd, W, U, bias,
                                                       out, hb32, cb32, flags);
}